// Round 7
// baseline (266.881 us; speedup 1.0000x reference)
//
#include <hip/hip_runtime.h>
#include <hip/hip_bf16.h>
#include <math.h>

// GAT on two 512-node cliques + bipartite cross edges, 5 GATConv layers.
// Dense-in-disguise edges: "inside" = clique within each set (+self),
// "cross" = full bipartite to opposite set (+self).
//
// R7: direct dense layers (math validated R3/R4/R6, absmax 0) with the
// broadcast operands moved OFF the LDS pipe: per layer, mmh writes
// hT / s'T / d'T (s',d' pre-scaled by log2e*a_src/a_dst) to global; att's
// inner 512-loop reads s'/h with block-uniform indices -> compiler emits
// s_load (SGPR broadcast, scalar pipe) -> loop is pure VALU+trans:
// add, mul, max, exp2, add, fma per term. No LDS, no vector loads in loop.
// All internal f32; input/output dtype runtime-detected f32/bf16.

typedef __hip_bfloat16 bf16;

#define LOG2E 1.44269504f

__device__ __forceinline__ float b2f(bf16 x) { return __bfloat162float(x); }

__device__ __forceinline__ int detect_bf16(const void* desc1) {
  const unsigned* u = (const unsigned*)desc1;
  int hits = 0;
#pragma unroll 8
  for (int i = 0; i < 256; ++i) {
    unsigned e = (u[i] >> 7) & 0xFFu;
    hits += (e >= 100u && e <= 140u) ? 1 : 0;
  }
  return hits >= 200 ? 1 : 0;
}

__device__ __forceinline__ float load_in(const void* p, int i, int bf) {
  return bf ? b2f(((const bf16*)p)[i]) : ((const float*)p)[i];
}

// ---------------------------------------------------------------- prep ----
__global__ __launch_bounds__(256) void prep_kernel(
    const void* __restrict__ desc1, const void* __restrict__ desc2,
    const void* __restrict__ W1,   const void* __restrict__ as1,
    const void* __restrict__ ad1,  const void* __restrict__ b1,
    const void* __restrict__ W2,   const void* __restrict__ as2,
    const void* __restrict__ ad2,  const void* __restrict__ b2,
    float* __restrict__ xt, float* __restrict__ W1f, float* __restrict__ W2f,
    float* __restrict__ vecs, int* __restrict__ flag) {
  const int bf = detect_bf16(desc1);
  if (blockIdx.x == 0 && threadIdx.x == 0) *flag = bf;
  const int total = 131072 + 16384 + 16384 + 6 * 128;
  for (int idx = blockIdx.x * blockDim.x + threadIdx.x; idx < total;
       idx += gridDim.x * blockDim.x) {
    if (idx < 131072) {
      int n = idx & 1023, c = idx >> 10;
      float v = (n < 512) ? load_in(desc1, n * 128 + c, bf)
                          : load_in(desc2, (n - 512) * 128 + c, bf);
      xt[idx] = v;  // xt[c*1024 + n]
    } else if (idx < 147456) {
      W1f[idx - 131072] = load_in(W1, idx - 131072, bf);
    } else if (idx < 163840) {
      W2f[idx - 147456] = load_in(W2, idx - 147456, bf);
    } else {
      int i = idx - 163840, o = i & 127;
      float v;
      if      (i < 128) v = load_in(as1, o, bf);
      else if (i < 256) v = load_in(ad1, o, bf);
      else if (i < 384) v = load_in(b1, o, bf);
      else if (i < 512) v = load_in(as2, o, bf);
      else if (i < 640) v = load_in(ad2, o, bf);
      else              v = load_in(b2, o, bf);
      vecs[i] = v;
    }
  }
}

// ------------------------------------------------------------------ mmh ----
// Per (hd, S): h column; writes hT, s'T = log2e*a_src*h, d'T = log2e*a_dst*h.
__global__ __launch_bounds__(512) void mmh_kernel(
    const float* __restrict__ xt_in, const float* __restrict__ Wf,
    const float* __restrict__ vecs,
    float* __restrict__ hT, float* __restrict__ spT, float* __restrict__ dpT) {
  const int hd = blockIdx.x & 127;
  const int S  = blockIdx.x >> 7;
  const int n  = S * 512 + threadIdx.x;
  float acca = 0.f, accb = 0.f;
#pragma unroll 8
  for (int k = 0; k < 128; k += 2) {
    acca = fmaf(xt_in[k * 1024 + n],       Wf[k * 128 + hd],       acca);
    accb = fmaf(xt_in[(k + 1) * 1024 + n], Wf[(k + 1) * 128 + hd], accb);
  }
  const float h = acca + accb;
  hT[hd * 1024 + n]  = h;
  spT[hd * 1024 + n] = h * (LOG2E * vecs[hd]);
  dpT[hd * 1024 + n] = h * (LOG2E * vecs[128 + hd]);
}

// ------------------------------------------------------------------ att ----
// grid 256 = (S<<7)|hd, 512 threads.  Sources = set S; dst = S (inside) or
// 1-S (cross).  Inner loop: block-uniform s'/h reads (scalar pipe), per term
// p = 2^max(t', .2t') with t' = s'_j + d'_i  (= exp(lrelu(s+d))).
template <int CROSS>
__global__ __launch_bounds__(512) void att_kernel(
    const float* __restrict__ hT, const float* __restrict__ spT,
    const float* __restrict__ dpT, const float* __restrict__ vecs,
    float* __restrict__ xt_out) {
  const int tid = threadIdx.x;
  const int hd  = blockIdx.x & 127;
  const int S   = blockIdx.x >> 7;
  const int D   = CROSS ? (1 - S) : S;
  const float bias = vecs[256 + hd];

  const float* sB = spT + hd * 1024 + S * 512;  // block-uniform reads
  const float* hB = hT  + hd * 1024 + S * 512;
  const int nd = D * 512 + tid;
  const float d_own = dpT[hd * 1024 + nd];      // per-thread (coalesced)

  float den0 = 0.f, den1 = 0.f, den2 = 0.f, den3 = 0.f;
  float num0 = 0.f, num1 = 0.f, num2 = 0.f, num3 = 0.f;
#pragma unroll 2
  for (int j0 = 0; j0 < 512; j0 += 8) {
    float sv[8], hv[8];
#pragma unroll
    for (int u = 0; u < 8; ++u) { sv[u] = sB[j0 + u]; hv[u] = hB[j0 + u]; }
    float p[8];
#pragma unroll
    for (int u = 0; u < 8; ++u) {
      float t = sv[u] + d_own;
      p[u] = exp2f(fmaxf(t, 0.2f * t));
    }
    den0 += p[0]; num0 = fmaf(p[0], hv[0], num0);
    den1 += p[1]; num1 = fmaf(p[1], hv[1], num1);
    den2 += p[2]; num2 = fmaf(p[2], hv[2], num2);
    den3 += p[3]; num3 = fmaf(p[3], hv[3], num3);
    den0 += p[4]; num0 = fmaf(p[4], hv[4], num0);
    den1 += p[5]; num1 = fmaf(p[5], hv[5], num1);
    den2 += p[6]; num2 = fmaf(p[6], hv[6], num2);
    den3 += p[7]; num3 = fmaf(p[7], hv[7], num3);
  }
  float den = (den0 + den1) + (den2 + den3);
  float num = (num0 + num1) + (num2 + num3);
  if (CROSS) {  // self-loop: dst node's own source score
    float t = spT[hd * 1024 + nd] + d_own;
    float p = exp2f(fmaxf(t, 0.2f * t));
    den += p;
    num = fmaf(p, hT[hd * 1024 + nd], num);
  }
  float o = num / (den + 1e-16f) + bias;
  o = (o > 0.f) ? o : expm1f(o);  // ELU
  xt_out[hd * 1024 + nd] = o;
}

// ----------------------------------------------------- final layer: mm2 ----
// grid 512 x 256: 2 rows x 128 cols per block.  h2 = x@W2, s2/d2 row dots.
__global__ __launch_bounds__(256) void mm2_kernel(
    const float* __restrict__ xt_in, const float* __restrict__ W2f,
    const float* __restrict__ vecs, float* __restrict__ h2,
    float* __restrict__ s2, float* __restrict__ d2) {
  __shared__ float rs[256], rd[256];
  const int tid = threadIdx.x;
  const int row = blockIdx.x * 2 + (tid >> 7);
  const int c = tid & 127;
  float acca = 0.f, accb = 0.f;
#pragma unroll 8
  for (int k = 0; k < 128; k += 2) {
    acca = fmaf(xt_in[k * 1024 + row], W2f[k * 128 + c], acca);
    accb = fmaf(xt_in[(k + 1) * 1024 + row], W2f[(k + 1) * 128 + c], accb);
  }
  float acc = acca + accb;
  h2[row * 128 + c] = acc;
  rs[tid] = acc * vecs[384 + c];  // a_src2
  rd[tid] = acc * vecs[512 + c];  // a_dst2
  __syncthreads();
  for (int off = 64; off > 0; off >>= 1) {
    if ((tid & 127) < off) { rs[tid] += rs[tid + off]; rd[tid] += rd[tid + off]; }
    __syncthreads();
  }
  if ((tid & 127) == 0) {
    s2[row] = rs[tid];
    d2[row] = rd[tid];
  }
}

// ---------------------------------------------------- final layer: attn ----
// Final conv: heads=1, ch=128, cross edges + self, no ELU, +b2.
// grid 256 x 256: 4 dst per block; thread (g,c) handles dsts dstBase+2g,+2g+1
// for channel c.  p staged in LDS; inner loop: 1 coalesced h2 load + 1
// float2 LDS broadcast serves 2 terms.
__global__ __launch_bounds__(256) void att2_kernel(
    const float* __restrict__ h2, const float* __restrict__ s2,
    const float* __restrict__ d2, const float* __restrict__ vecs,
    void* __restrict__ out, const int* __restrict__ flag) {
  __shared__ __align__(16) float pT[512 * 4];  // pT[j*4 + ld]
  const int tid = threadIdx.x;
  const int dstBase = blockIdx.x * 4;
  const int srcBase = (dstBase < 512) ? 512 : 0;  // cross edges

  for (int e = tid; e < 2048; e += 256) {
    int j = e >> 2, ld = e & 3;
    float t = s2[srcBase + j] + d2[dstBase + ld];
    pT[e] = __expf(fmaxf(t, 0.2f * t));
  }
  __syncthreads();

  const int c = tid & 127;
  const int g = tid >> 7;            // 0 or 1 -> dst pair
  const int i0 = dstBase + 2 * g, i1 = i0 + 1;
  float den0 = 0.f, num0 = 0.f, den1 = 0.f, num1 = 0.f;
  const float* hrow = h2 + srcBase * 128 + c;
#pragma unroll 4
  for (int j = 0; j < 512; ++j) {
    float2 pv = *(const float2*)(pT + j * 4 + 2 * g);
    float hval = hrow[j * 128];
    den0 += pv.x; num0 = fmaf(pv.x, hval, num0);
    den1 += pv.y; num1 = fmaf(pv.y, hval, num1);
  }
  // self-loops
  float ts0 = s2[i0] + d2[i0];
  float ps0 = __expf(fmaxf(ts0, 0.2f * ts0));
  den0 += ps0; num0 = fmaf(ps0, h2[i0 * 128 + c], num0);
  float ts1 = s2[i1] + d2[i1];
  float ps1 = __expf(fmaxf(ts1, 0.2f * ts1));
  den1 += ps1; num1 = fmaf(ps1, h2[i1 * 128 + c], num1);

  float o0 = num0 / (den0 + 1e-16f) + vecs[640 + c];
  float o1 = num1 / (den1 + 1e-16f) + vecs[640 + c];
  if (*flag) {
    ((bf16*)out)[i0 * 128 + c] = __float2bfloat16(o0);
    ((bf16*)out)[i1 * 128 + c] = __float2bfloat16(o1);
  } else {
    ((float*)out)[i0 * 128 + c] = o0;
    ((float*)out)[i1 * 128 + c] = o1;
  }
}

// ------------------------------------------------------------- launcher ----
extern "C" void kernel_launch(void* const* d_in, const int* in_sizes, int n_in,
                              void* d_out, int out_size, void* d_ws, size_t ws_size,
                              hipStream_t stream) {
  (void)in_sizes; (void)n_in; (void)out_size; (void)ws_size;
  float* ws   = (float*)d_ws;
  float* xtA  = ws;            // 131072
  float* xtB  = ws + 131072;   // 131072
  float* hT   = ws + 262144;   // 131072
  float* spT  = ws + 393216;   // 131072
  float* dpT  = ws + 524288;   // 131072
  float* h2   = ws + 655360;   // 131072
  float* W1f  = ws + 786432;   // 16384
  float* W2f  = ws + 802816;   // 16384
  float* vecs = ws + 819200;   // 768
  float* s2   = ws + 819968;   // 1024
  float* d2   = ws + 820992;   // 1024
  int*   flag = (int*)(ws + 822016);  // ~3.3 MB total

  prep_kernel<<<64, 256, 0, stream>>>(d_in[0], d_in[1], d_in[2], d_in[3],
                                      d_in[4], d_in[5], d_in[6], d_in[7],
                                      d_in[8], d_in[9], xtA, W1f, W2f, vecs, flag);
  // layer 1: inside
  mmh_kernel<<<256, 512, 0, stream>>>(xtA, W1f, vecs, hT, spT, dpT);
  att_kernel<0><<<256, 512, 0, stream>>>(hT, spT, dpT, vecs, xtB);
  // layer 2: cross
  mmh_kernel<<<256, 512, 0, stream>>>(xtB, W1f, vecs, hT, spT, dpT);
  att_kernel<1><<<256, 512, 0, stream>>>(hT, spT, dpT, vecs, xtA);
  // layer 3: inside
  mmh_kernel<<<256, 512, 0, stream>>>(xtA, W1f, vecs, hT, spT, dpT);
  att_kernel<0><<<256, 512, 0, stream>>>(hT, spT, dpT, vecs, xtB);
  // layer 4: cross
  mmh_kernel<<<256, 512, 0, stream>>>(xtB, W1f, vecs, hT, spT, dpT);
  att_kernel<1><<<256, 512, 0, stream>>>(hT, spT, dpT, vecs, xtA);
  // final layer
  mm2_kernel<<<512, 256, 0, stream>>>(xtA, W2f, vecs, h2, s2, d2);
  att2_kernel<<<256, 256, 0, stream>>>(h2, s2, d2, vecs, d_out, flag);
}